// Round 7
// baseline (2324.254 us; speedup 1.0000x reference)
//
#include <hip/hip_runtime.h>
#include <math.h>

#define HIDN 320
#define DIMN 64

// workspace float layout
#define W1T_OFF 0          // [64][320]        w1row[i][h'] = (M1*W1)[perm1[h'], i]
#define W2T_OFF 20480      // [40][20][16][8]  w2[hc][gb][j][u] = (M2*W2)[perm2[gb*16+j], perm1[hc*8+u]]
#define W3I_OFF 122880     // [64][16][40]     w3[i][j][2k+c] = (M3*W3)[i+64c, perm2[16k+j]]
#define B1P_OFF 163840     // [320] b1[perm1]
#define B2P_OFF 164160     // [320] b2[perm2]
#define FTOT    164480
// workspace int layout (after floats): perm1[320] perm2[320] start1[65] start2[65]

__global__ __launch_bounds__(320) void maf_setup(const float* __restrict__ M1,
                                                 const float* __restrict__ M3,
                                                 int* __restrict__ wsi) {
  __shared__ int m0[HIDN], m1[HIDN];
  __shared__ int c1[64], c2[64];
  __shared__ int s1[65], s2[65];
  int t = threadIdx.x;
  if (t < 64) { c1[t] = 0; c2[t] = 0; }
  __syncthreads();
  if (t < HIDN) {
    float s = 0.f;
    for (int d = 0; d < DIMN; ++d) s += M1[t * DIMN + d];
    int a = (int)(s + 0.5f) - 1;          // m0 in [0,62]
    m0[t] = a;
    atomicAdd(&c1[a], 1);
    float sb = 0.f;
    for (int o = 0; o < DIMN; ++o) sb += M3[o * HIDN + t];
    int b = 63 - (int)(sb + 0.5f);        // m1 in [0,62]
    m1[t] = b;
    atomicAdd(&c2[b], 1);
  }
  __syncthreads();
  if (t == 0) {
    int a = 0;
    for (int v = 0; v < 64; ++v) { s1[v] = a; a += c1[v]; }
    s1[64] = a;
    a = 0;
    for (int v = 0; v < 64; ++v) { s2[v] = a; a += c2[v]; }
    s2[64] = a;
  }
  __syncthreads();
  if (t < HIDN) {
    int key = m0[t], rk = 0;
    for (int h = 0; h < t; ++h) rk += (m0[h] == key);
    wsi[s1[key] + rk] = t;                 // perm1
    int key2 = m1[t], rk2 = 0;
    for (int g = 0; g < t; ++g) rk2 += (m1[g] == key2);
    wsi[320 + s2[key2] + rk2] = t;         // perm2
  }
  if (t < 65) { wsi[640 + t] = s1[t]; wsi[705 + t] = s2[t]; }
}

__global__ void maf_fill(const float* __restrict__ W1, const float* __restrict__ b1,
                         const float* __restrict__ W2, const float* __restrict__ b2,
                         const float* __restrict__ W3,
                         const float* __restrict__ M1, const float* __restrict__ M2,
                         const float* __restrict__ M3,
                         const int* __restrict__ wsi, float* __restrict__ wsf) {
  int idx = blockIdx.x * blockDim.x + threadIdx.x;
  const int* p1 = wsi;
  const int* p2 = wsi + 320;
  if (idx < 20480) {                       // w1row[i][hp]
    int i = idx / 320, hp = idx % 320;
    int h = p1[hp];
    wsf[W1T_OFF + idx] = M1[h * 64 + i] * W1[h * 64 + i];
  } else if (idx < 122880) {               // w2[hc][gb][jj][u]
    int e = idx - 20480;
    int u = e & 7;
    int jj = (e >> 3) & 15;
    int q = e >> 7;                        // hc*20 + gb
    int gb = q % 20, hc = q / 20;
    int gp = gb * 16 + jj, hp = hc * 8 + u;
    int h = p1[hp], g = p2[gp];
    wsf[idx] = M2[g * HIDN + h] * W2[g * HIDN + h];
  } else if (idx < 163840) {               // w3[i][jj][2k+c]
    int e = idx - 122880;
    int c = e & 1;
    int k = (e % 40) >> 1;
    int jj = (e / 40) & 15;
    int i = e / 640;
    int gp = k * 16 + jj;
    int g = p2[gp];
    int row = i + (c ? 64 : 0);
    wsf[idx] = M3[row * HIDN + g] * W3[row * HIDN + g];
  } else if (idx < 164160) {
    wsf[idx] = b1[p1[idx - 163840]];
  } else if (idx < 164480) {
    wsf[idx] = b2[p2[idx - 164160]];
  }
}

#define RWS 16     // (b,t) rows per workgroup (256 threads, 4 waves)
#define H1S 328    // h1p LDS row stride (8 mod 32 -> 2-way bank aliasing = free)

// ---- scatter chunk macros: depth-2 software pipeline, all-static indices ----
#define LOADC(B, C)                                                   \
  _Pragma("unroll")                                                   \
  for (int kk = 0; kk < 4; ++kk) {                                    \
    const float* cp = w2t + ((C) * 4 + kk) * 128;                     \
    Qa[B][kk] = *reinterpret_cast<const float4*>(cp);                 \
    Qb[B][kk] = *reinterpret_cast<const float4*>(cp + 4);             \
  }

#define FMAC(B, C)                                                    \
  _Pragma("unroll")                                                   \
  for (int kk = 0; kk < 4; ++kk) {                                    \
    const int k = (C) * 4 + kk;                                       \
    float acc = h2[k];                                                \
    acc = fmaf(Qa[B][kk].x, av[0], acc);                              \
    acc = fmaf(Qa[B][kk].y, av[1], acc);                              \
    acc = fmaf(Qa[B][kk].z, av[2], acc);                              \
    acc = fmaf(Qa[B][kk].w, av[3], acc);                              \
    acc = fmaf(Qb[B][kk].x, av[4], acc);                              \
    acc = fmaf(Qb[B][kk].y, av[5], acc);                              \
    acc = fmaf(Qb[B][kk].z, av[6], acc);                              \
    acc = fmaf(Qb[B][kk].w, av[7], acc);                              \
    h2[k] = acc;                                                      \
  }

#define SCATTER_BODY(HB, Ai, Bi, WAi, WBi)                            \
  {                                                                   \
    float av[8];                                                      \
    {                                                                 \
      float hv[8] = {Ai.x, Ai.y, Ai.z, Ai.w, Bi.x, Bi.y, Bi.z, Bi.w};\
      float wv[8] = {WAi.x, WAi.y, WAi.z, WAi.w,                      \
                     WBi.x, WBi.y, WBi.z, WBi.w};                     \
      _Pragma("unroll")                                               \
      for (int u = 0; u < 8; ++u) {                                   \
        const int hp = (HB) + u;                                      \
        float a = fmaf(wv[u], xi, hv[u]);                             \
        av[u] = (hp >= h0 && hp < h1e) ? fmaxf(a, 0.f) : 0.f;         \
      }                                                               \
    }                                                                 \
    const float* w2t = wsf + W2T_OFF + ((HB) >> 3) * 2560 + j * 8;    \
    float4 Qa[2][4], Qb[2][4];                                        \
    LOADC(0, 0)                                                       \
    LOADC(1, 1)                                                       \
    FMAC(0, 0)                                                        \
    LOADC(0, 2)                                                       \
    FMAC(1, 1)                                                        \
    LOADC(1, 3)                                                       \
    FMAC(0, 2)                                                        \
    LOADC(0, 4)                                                       \
    FMAC(1, 3)                                                        \
    FMAC(0, 4)                                                        \
  }

__global__ __launch_bounds__(256, 2) void maf_main(
    const float* __restrict__ z, const float* __restrict__ b3,
    const float* __restrict__ wsf, const int* __restrict__ wsi,
    float* __restrict__ out) {
  __shared__ float h1p[RWS * H1S];
  __shared__ float zx[RWS * 64];           // z-reversed in, x out (in-place per step)
  __shared__ float b3s[128];
  __shared__ int s1s[65];

  const int tid = threadIdx.x;
  const int r = tid >> 4;    // row within block (0..15); 4 rows per wave
  const int j = tid & 15;    // lane within row-group
  const long long bt0 = (long long)blockIdx.x * RWS;

  float* h1r = h1p + r * H1S;

  // row-local h1 init
  for (int c = j; c < HIDN; c += 16) h1r[c] = wsf[B1P_OFF + c];

  // load reversed z rows (coalesced)
  for (int k = tid; k < RWS * 64; k += 256) {
    int rr = k >> 6, c = k & 63;
    zx[k] = z[(bt0 + rr) * 64 + (63 - c)];
  }
  if (tid < 65) s1s[tid] = wsi[640 + tid];
  if (tid < 128) b3s[tid] = b3[tid];

  // h2 pre-activations: register-resident, lane j owns g' = j + 16k
  float h2[20];
#pragma unroll
  for (int k = 0; k < 20; ++k) h2[k] = wsf[B2P_OFF + j + 16 * k];

  __syncthreads();           // init fence (cross-wave LDS init above)

  // prefetch gather weights for step 0
  float4 G[10];
#pragma unroll
  for (int m = 0; m < 10; ++m)
    G[m] = *reinterpret_cast<const float4*>(wsf + W3I_OFF + j * 40 + 4 * m);

  float logdet = 0.f;

  for (int i = 0; i < 64; ++i) {
    // raw barrier: no cross-wave LDS dependency exists (h1/zx rows are
    // wave-private); this only keeps waves in phase for L1 weight sharing.
    __builtin_amdgcn_s_barrier();

    const int h0  = __builtin_amdgcn_readfirstlane(s1s[i]);
    const int h1e = __builtin_amdgcn_readfirstlane(s1s[i + 1]);
    const int hb0 = h0 & ~7;
    const float* w1row = wsf + W1T_OFF + i * HIDN;
    const float zi = zx[(r << 6) + i];

    // early finalize loads (independent of xi; overlap gather/butterfly/exp)
    float4 A0  = *reinterpret_cast<const float4*>(&h1r[hb0]);
    float4 B0  = *reinterpret_cast<const float4*>(&h1r[hb0 + 4]);
    float4 Wa0 = *reinterpret_cast<const float4*>(w1row + hb0);
    float4 Wb0 = *reinterpret_cast<const float4*>(w1row + hb0 + 4);

    // ---- gather s_i, t_i from prefetched G (zero load latency) ----
    float sa[4] = {0.f, 0.f, 0.f, 0.f};
    float ta[4] = {0.f, 0.f, 0.f, 0.f};
#pragma unroll
    for (int m = 0; m < 10; ++m) {
      float v0 = fmaxf(h2[2 * m], 0.f);
      float v1 = fmaxf(h2[2 * m + 1], 0.f);
      sa[m & 3] = fmaf(G[m].x, v0, sa[m & 3]);
      ta[m & 3] = fmaf(G[m].y, v0, ta[m & 3]);
      sa[m & 3] = fmaf(G[m].z, v1, sa[m & 3]);
      ta[m & 3] = fmaf(G[m].w, v1, ta[m & 3]);
    }
    float ss = (sa[0] + sa[1]) + (sa[2] + sa[3]);
    float tt = (ta[0] + ta[1]) + (ta[2] + ta[3]);
#pragma unroll
    for (int m = 1; m < 16; m <<= 1) {     // butterfly within 16-lane row group
      ss += __shfl_xor(ss, m);
      tt += __shfl_xor(tt, m);
    }
    ss += b3s[i];
    tt += b3s[64 + i];
    const float xi = (zi - tt) * __expf(-ss);
    logdet -= ss;
    zx[(r << 6) + i] = xi;                 // all 16 lanes write same value

    // ---- finalize block(i) of layer-1, scatter into h2 regs ----
    // dense over g' (w2 == 0 for finalized g'); range mask on av only.
    if (hb0 < h1e) SCATTER_BODY(hb0, A0, B0, Wa0, Wb0);
    for (int hb = hb0 + 8; hb < h1e; hb += 8) {
      float4 A  = *reinterpret_cast<const float4*>(&h1r[hb]);
      float4 Bv = *reinterpret_cast<const float4*>(&h1r[hb + 4]);
      float4 Wa = *reinterpret_cast<const float4*>(w1row + hb);
      float4 Wb = *reinterpret_cast<const float4*>(w1row + hb + 4);
      SCATTER_BODY(hb, A, Bv, Wa, Wb);
    }

    // ---- suffix layer-1 update: batched loads, predicated LDS RMW ----
    float wls[20];
#pragma unroll
    for (int k = 0; k < 20; ++k) wls[k] = w1row[j + 16 * k];

    // prefetch gather weights for next step (completes during barrier/suffix)
    const int ip = (i < 63) ? i + 1 : 63;
    const float* w3n = wsf + W3I_OFF + (ip * 16 + j) * 40;
#pragma unroll
    for (int m = 0; m < 10; ++m)
      G[m] = *reinterpret_cast<const float4*>(w3n + 4 * m);

#pragma unroll
    for (int k = 0; k < 20; ++k) {
      const int hp = j + 16 * k;
      if (hp >= h1e) h1r[hp] = fmaf(wls[k], xi, h1r[hp]);
    }
  }

  // ---- writeout ----
#pragma unroll
  for (int u = 0; u < 4; ++u) {
    int c = j + 16 * u;
    float v = zx[(r << 6) + c];
    v = fminf(fmaxf(v, -100.f), 100.f);
    out[(bt0 + r) * 64 + c] = v;
  }
  if (j == 0) {
    float v = fminf(fmaxf(logdet, -100.f), 100.f);
    out[4194304LL + bt0 + r] = v;
  }
}

extern "C" void kernel_launch(void* const* d_in, const int* in_sizes, int n_in,
                              void* d_out, int out_size, void* d_ws, size_t ws_size,
                              hipStream_t stream) {
  const float* z  = (const float*)d_in[0];
  const float* W1 = (const float*)d_in[1];
  const float* b1 = (const float*)d_in[2];
  const float* W2 = (const float*)d_in[3];
  const float* b2 = (const float*)d_in[4];
  const float* W3 = (const float*)d_in[5];
  const float* b3 = (const float*)d_in[6];
  const float* M1 = (const float*)d_in[7];
  const float* M2 = (const float*)d_in[8];
  const float* M3 = (const float*)d_in[9];
  float* out = (float*)d_out;
  float* wsf = (float*)d_ws;
  int* wsi = (int*)((char*)d_ws + (size_t)FTOT * sizeof(float));

  if (ws_size < (size_t)FTOT * sizeof(float) + 770 * sizeof(int)) return;

  maf_setup<<<1, 320, 0, stream>>>(M1, M3, wsi);
  maf_fill<<<(164480 + 255) / 256, 256, 0, stream>>>(W1, b1, W2, b2, W3, M1, M2, M3, wsi, wsf);
  maf_main<<<4096, 256, 0, stream>>>(z, b3, wsf, wsi, out);
}